// Round 16
// baseline (90.338 us; speedup 1.0000x reference)
//
#include <hip/hip_runtime.h>

typedef float  f32x4  __attribute__((ext_vector_type(4)));
typedef short  s16x8  __attribute__((ext_vector_type(8)));
typedef short  s16x4  __attribute__((ext_vector_type(4)));

#define NROWS (2048 * 128)
#define PASSES 8         // 16-row passes per wave; 512 blocks x 4 waves x 8 x 16
#define HS 104           // act LDS stride in shorts
#define EPSF 1e-8f
#define GRID (NROWS / (4 * PASSES * 16))   // 512 blocks

union Frag { s16x8 v; unsigned short u[8]; };

// fp32 -> bf16 RTNE (verified R3-R15, absmax 0.0)
__device__ __forceinline__ unsigned short f2bf(float f) {
    unsigned int u = __float_as_uint(f);
    u += 0x7fffu + ((u >> 16) & 1u);
    return (unsigned short)(u >> 16);
}

// ---------------------------------------------------------------------------
// SINGLE FUSED KERNEL (R15 main loop, byte-identical; repack + finalize
// folded in). Eliminates 2 serialized launches (repack 52-blk + finalize)
// from the graph's critical path and the w2f/w3f global intermediates.
//  - W1 + biases: repacked from RAW W1/b* straight into block LDS (same
//    lane math as the old repack kernel; overlaps stage(0) flight).
//  - W2r/W3r: repacked from RAW W2/W3 directly into registers per wave
//    (2 x f32x4 + cvt per frag; pad rows/cols predicated to zero; loads
//    never straddle a row: kb is a multiple of 8, rows are 96/72 floats).
//  - Finalize: last-block pattern -- __threadfence, counter atomic in the
//    memset-zeroed acc page, coherent atomic-reads of acc, write d_out.
// ---------------------------------------------------------------------------
__global__ __launch_bounds__(256, 1)
void mlp_fused(const float* __restrict__ x,
               const float* __restrict__ W1, const float* __restrict__ b1,
               const float* __restrict__ W2, const float* __restrict__ b2,
               const float* __restrict__ W3, const float* __restrict__ b3,
               float* __restrict__ acc,   // [65]: s[64], uu ; +counter at [65]
               float* __restrict__ out)
{
    __shared__ __align__(16) unsigned char  wb[25536];        // W1 frags | b1 | b2 | b3
    __shared__ __align__(16) float          xbuf[4][2048];    // 32 KB: 8 KB/wave x tile
    __shared__ __align__(16) unsigned short act[4][16][HS];   // 13.3 KB wave-private
    __shared__ float sred[4][64];
    __shared__ float uured[4];
    __shared__ unsigned last_flag;

    const unsigned short* w1L = (const unsigned short*)wb;    // 24 frags
    unsigned short* w1Lw = (unsigned short*)wb;
    float* wbias = (float*)(wb + 24576);                      // b1[96] b2[80] b3[64]
    const float* b1L = (const float*)(wb + 24576);
    const float* b2L = b1L + 96;
    const float* b3L = b1L + 176;

    const int tid  = threadIdx.x;
    const int lane = tid & 63;
    const int wv   = tid >> 6;
    const int g    = lane >> 4;
    const int sl   = lane & 15;
    const int g4   = g * 4;
    const int wave_gid = blockIdx.x * 4 + wv;     // 0..2047; wave owns 128 rows

    // ---- async stage of pass p's 16-row x tile (8 KB), swizzled source ----
    auto stage = [&](int p) {
        const char* tb = (const char*)x
                       + ((size_t)wave_gid * 128 + (size_t)p * 16) * 512;
        float* dst = &xbuf[wv][0];
#pragma unroll
        for (int c = 0; c < 8; ++c) {
            const unsigned off = (unsigned)(c * 1024 + lane * 16);
            const unsigned so  = off ^ (((off >> 9) & 7u) << 4);
            __builtin_amdgcn_global_load_lds(
                (const __attribute__((address_space(1))) void*)(tb + so),
                (__attribute__((address_space(3))) void*)(dst + c * 256),
                16, 0, 0);
        }
    };

    stage(0);                                   // in flight during weight repack

    // ---- repack W1 from RAW into LDS: 24 frags x 64 lanes = 1536 slots ----
    // slot i: f = i>>6 (nt = f>>2, ks = f&3), l = i&63;
    // data = W1[(nt*16 + (l&15))*128 + ks*32 + (l>>4)*8 + j], j = 0..7
#pragma unroll
    for (int it = 0; it < 6; ++it) {
        const int i = it * 256 + tid;
        const int f = i >> 6, l = i & 63;
        const int o  = ((f >> 2) * 16) + (l & 15);
        const int kb = ((f & 3) * 32) + ((l >> 4) * 8);
        const f32x4 u0 = *(const f32x4*)(W1 + o * 128 + kb);
        const f32x4 u1 = *(const f32x4*)(W1 + o * 128 + kb + 4);
        s16x8 v;
#pragma unroll
        for (int j = 0; j < 4; ++j) { v[j] = (short)f2bf(u0[j]); v[4 + j] = (short)f2bf(u1[j]); }
        *(s16x8*)&w1Lw[f * 512 + l * 8] = v;
    }
    // ---- biases (zero-padded) into LDS ----
    if (tid < 240) {
        float bv;
        if (tid < 96)       bv = b1[tid];
        else if (tid < 176) { const int o = tid - 96; bv = (o < 72) ? b2[o] : 0.f; }
        else                bv = b3[tid - 176];
        wbias[tid] = bv;
    }

    // ---- repack W2/W3 from RAW directly into registers (loop-invariant) ----
    Frag W2r[5][3], W3r[4][3];
#pragma unroll
    for (int nt = 0; nt < 5; ++nt)
#pragma unroll
        for (int ks = 0; ks < 3; ++ks) {
            const int o = nt * 16 + sl, kb = ks * 32 + g * 8;
            if (o < 72) {
                const f32x4 u0 = *(const f32x4*)(W2 + o * 96 + kb);
                const f32x4 u1 = *(const f32x4*)(W2 + o * 96 + kb + 4);
#pragma unroll
                for (int j = 0; j < 4; ++j) {
                    W2r[nt][ks].u[j]     = f2bf(u0[j]);
                    W2r[nt][ks].u[4 + j] = f2bf(u1[j]);
                }
            } else {
                W2r[nt][ks].v = (s16x8){0, 0, 0, 0, 0, 0, 0, 0};
            }
        }
#pragma unroll
    for (int nt = 0; nt < 4; ++nt)
#pragma unroll
        for (int ks = 0; ks < 3; ++ks) {
            const int o = nt * 16 + sl, kb = ks * 32 + g * 8;
            if (kb < 72) {          // kb mult of 8; never straddles 72
                const f32x4 u0 = *(const f32x4*)(W3 + o * 72 + kb);
                const f32x4 u1 = *(const f32x4*)(W3 + o * 72 + kb + 4);
#pragma unroll
                for (int j = 0; j < 4; ++j) {
                    W3r[nt][ks].u[j]     = f2bf(u0[j]);
                    W3r[nt][ks].u[4 + j] = f2bf(u1[j]);
                }
            } else {
                W3r[nt][ks].v = (s16x8){0, 0, 0, 0, 0, 0, 0, 0};
            }
        }

    __syncthreads();                            // weights visible; stage(0) drained

    float uu_part = 0.f;
    float s_part[4][4];
#pragma unroll
    for (int nt = 0; nt < 4; ++nt)
#pragma unroll
        for (int r = 0; r < 4; ++r) s_part[nt][r] = 0.f;

#pragma unroll 1
    for (int p = 0; p < PASSES; ++p) {
        // wait for this pass's staged tile
        asm volatile("s_waitcnt vmcnt(0)" ::: "memory");
        __builtin_amdgcn_sched_barrier(0);

        // ---- read x from LDS (swizzled) -> regs, cvt to B-frags (samples) ----
        const char* xb = (const char*)&xbuf[wv][0];
        const unsigned sw = (unsigned)((sl & 7) << 4);
        f32x4 t[8];
#pragma unroll
        for (int ks = 0; ks < 4; ++ks)
#pragma unroll
            for (int h = 0; h < 2; ++h)
                t[ks * 2 + h] = *(const f32x4*)(
                    xb + sl * 512 + ks * 128 + (((unsigned)(g * 32 + h * 16)) ^ sw));
        Frag X1[4];
#pragma unroll
        for (int ks = 0; ks < 4; ++ks)
#pragma unroll
            for (int j = 0; j < 4; ++j) {
                X1[ks].u[j]     = f2bf(t[ks * 2 + 0][j]);
                X1[ks].u[4 + j] = f2bf(t[ks * 2 + 1][j]);
            }

        // buffer free: issue next pass's stage; overlaps compute below
        __builtin_amdgcn_sched_barrier(0);
        if (p + 1 < PASSES) stage(p + 1);

        // ========== layer 1: D1 = W1 x x^T  (W1 = A operand, from LDS) ==========
        f32x4 D1[6];
#pragma unroll
        for (int nt = 0; nt < 6; ++nt)
            D1[nt] = *(const f32x4*)&b1L[nt * 16 + g4];
#pragma unroll
        for (int ks = 0; ks < 4; ++ks)
#pragma unroll
            for (int nt = 0; nt < 6; ++nt) {
                const s16x8 Wf = *(const s16x8*)&w1L[(nt * 4 + ks) * 512 + lane * 8];
                D1[nt] = __builtin_amdgcn_mfma_f32_16x16x32_bf16(Wf, X1[ks].v, D1[nt], 0, 0, 0);
            }
        // relu + contiguous b64 write: act[sample=sl][feat nt*16+g4 .. +3]
#pragma unroll
        for (int nt = 0; nt < 6; ++nt) {
            s16x4 q;
#pragma unroll
            for (int j = 0; j < 4; ++j) q[j] = (short)f2bf(fmaxf(D1[nt][j], 0.f));
            *(s16x4*)&act[wv][sl][nt * 16 + g4] = q;
        }

        // layer-2 B-frags: feats 0..95 of sample sl
        Frag A2[3];
#pragma unroll
        for (int ks = 0; ks < 3; ++ks)
            A2[ks].v = *(const s16x8*)&act[wv][sl][ks * 32 + g * 8];

        // zero pad feats 80..95 for the h2 tile (read by L3 ks=2)
        {
            const s16x4 z = (s16x4){0, 0, 0, 0};
            *(s16x4*)&act[wv][sl][80 + g4] = z;
        }

        // ========== layer 2: D2 = W2 x h1^T (W2 from registers) ==========
        f32x4 D2[5];
#pragma unroll
        for (int nt = 0; nt < 5; ++nt)
            D2[nt] = *(const f32x4*)&b2L[nt * 16 + g4];
#pragma unroll
        for (int ks = 0; ks < 3; ++ks)
#pragma unroll
            for (int nt = 0; nt < 5; ++nt)
                D2[nt] = __builtin_amdgcn_mfma_f32_16x16x32_bf16(W2r[nt][ks].v, A2[ks].v, D2[nt], 0, 0, 0);
#pragma unroll
        for (int nt = 0; nt < 5; ++nt) {
            s16x4 q;
#pragma unroll
            for (int j = 0; j < 4; ++j) q[j] = (short)f2bf(fmaxf(D2[nt][j], 0.f));
            *(s16x4*)&act[wv][sl][nt * 16 + g4] = q;
        }

        // layer-3 B-frags: h2 feats 0..95 (72..95 structurally zero)
        Frag A3[3];
#pragma unroll
        for (int ks = 0; ks < 3; ++ks)
            A3[ks].v = *(const s16x8*)&act[wv][sl][ks * 32 + g * 8];

        // ========== layer 3: D3 = W3 x h2^T (W3 from registers) ==========
        f32x4 D3[4];
#pragma unroll
        for (int nt = 0; nt < 4; ++nt)
            D3[nt] = *(const f32x4*)&b3L[nt * 16 + g4];
#pragma unroll
        for (int ks = 0; ks < 3; ++ks)
#pragma unroll
            for (int nt = 0; nt < 4; ++nt)
                D3[nt] = __builtin_amdgcn_mfma_f32_16x16x32_bf16(W3r[nt][ks].v, A3[ks].v, D3[nt], 0, 0, 0);

        // ===== epilogue (swapped): lane (g,sl) holds 16 outs of sample sl =====
        float ff = 0.f;
#pragma unroll
        for (int nt = 0; nt < 4; ++nt)
#pragma unroll
            for (int r = 0; r < 4; ++r)
                ff = fmaf(D3[nt][r], D3[nt][r], ff);
        ff += __shfl_xor(ff, 16, 64);
        ff += __shfl_xor(ff, 32, 64);
        const float inv = 1.f / fmaxf(sqrtf(ff), EPSF);
        uu_part = fmaf(ff * inv, inv, uu_part);
#pragma unroll
        for (int nt = 0; nt < 4; ++nt)
#pragma unroll
            for (int r = 0; r < 4; ++r)
                s_part[nt][r] = fmaf(D3[nt][r], inv, s_part[nt][r]);
    }

    // ---- once per wave: s over sl lanes; uu over all lanes ----
#pragma unroll
    for (int nt = 0; nt < 4; ++nt)
#pragma unroll
        for (int r = 0; r < 4; ++r) {
            s_part[nt][r] += __shfl_xor(s_part[nt][r], 1, 64);
            s_part[nt][r] += __shfl_xor(s_part[nt][r], 2, 64);
            s_part[nt][r] += __shfl_xor(s_part[nt][r], 4, 64);
            s_part[nt][r] += __shfl_xor(s_part[nt][r], 8, 64);
        }
#pragma unroll
    for (int off = 1; off < 64; off <<= 1)
        uu_part += __shfl_xor(uu_part, off, 64);

    if (sl == 0) {
#pragma unroll
        for (int nt = 0; nt < 4; ++nt) {
            f32x4 v = {s_part[nt][0], s_part[nt][1], s_part[nt][2], s_part[nt][3]};
            *(f32x4*)&sred[wv][nt * 16 + g4] = v;
        }
    }
    if (lane == 0) uured[wv] = uu_part * 0.25f;
    __syncthreads();

    if (tid < 64) {
        const float t2 = sred[0][tid] + sred[1][tid] + sred[2][tid] + sred[3][tid];
        atomicAdd(&acc[tid], t2);
    }
    if (tid == 0)
        atomicAdd(&acc[64], uured[0] + uured[1] + uured[2] + uured[3]);

    // ---- last-block finalize (replaces the finalize_k launch) ----
    __threadfence();
    __syncthreads();          // barrier implies waitcnt: this block's atomics drained
    if (tid == 0) {
        const unsigned prev = atomicAdd((unsigned*)(acc + 65), 1u);
        last_flag = (prev == (unsigned)(GRID - 1)) ? 1u : 0u;
    }
    __syncthreads();
    if (last_flag && tid < 64) {
        __threadfence();                        // acquire: other blocks' acc visible
        const float s  = atomicAdd(&acc[tid], 0.f);   // coherent read
        float d = s * s;
#pragma unroll
        for (int off = 32; off > 0; off >>= 1)
            d += __shfl_xor(d, off, 64);
        if (tid == 0) {
            const float uu = atomicAdd(&acc[64], 0.f);
            out[0] = 0.5f * (d - uu) / (float)NROWS;
        }
    }
}

extern "C" void kernel_launch(void* const* d_in, const int* in_sizes, int n_in,
                              void* d_out, int out_size, void* d_ws, size_t ws_size,
                              hipStream_t stream)
{
    const float* x  = (const float*)d_in[0];
    const float* W1 = (const float*)d_in[1];
    const float* b1 = (const float*)d_in[2];
    const float* W2 = (const float*)d_in[3];
    const float* b2 = (const float*)d_in[4];
    const float* W3 = (const float*)d_in[5];
    const float* b3 = (const float*)d_in[6];

    float* acc = (float*)d_ws;   // [0..63] s, [64] uu, [65] done-counter
    hipMemsetAsync(acc, 0, 1024, stream);

    mlp_fused<<<GRID, 256, 0, stream>>>(x, W1, b1, W2, b2, W3, b3,
                                        acc, (float*)d_out);
}

// Round 17
// 52.130 us; speedup vs baseline: 1.7329x; 1.7329x over previous
//
#include <hip/hip_runtime.h>

typedef float  f32x4  __attribute__((ext_vector_type(4)));
typedef short  s16x8  __attribute__((ext_vector_type(8)));
typedef short  s16x4  __attribute__((ext_vector_type(4)));

#define NROWS (2048 * 128)
#define PASSES 8         // 16-row passes per wave; 512 blocks x 4 waves x 8 x 16
#define HS 104           // act LDS stride in shorts
#define EPSF 1e-8f

union Frag { s16x8 v; unsigned short u[8]; };

// fp32 -> bf16 RTNE (verified R3-R16, absmax 0.0)
__device__ __forceinline__ unsigned short f2bf(float f) {
    unsigned int u = __float_as_uint(f);
    u += 0x7fffu + ((u >> 16) & 1u);
    return (unsigned short)(u >> 16);
}

// ---------------------------------------------------------------------------
// Pre-kernel: repack weights to bf16 MFMA frag order (R15 exact; the clean
// frag-layout w2f/w3f loads are what lets the allocator HOLD the W2r/W3r
// register hoist -- R16's raw-pointer in-kernel repack lost it, VGPR 136).
// ws layout: [acc 1024][w1f 24576][b1 384][b2 320][b3 256][w2f 15360][w3f 12288]
// ---------------------------------------------------------------------------
__global__ void repack(const float* __restrict__ W1, const float* __restrict__ b1,
                       const float* __restrict__ W2, const float* __restrict__ b2,
                       const float* __restrict__ W3, const float* __restrict__ b3,
                       unsigned short* __restrict__ w1f, unsigned short* __restrict__ w2f,
                       unsigned short* __restrict__ w3f,
                       float* __restrict__ b1p, float* __restrict__ b2p,
                       float* __restrict__ b3p)
{
    const int b = blockIdx.x;
    const int l = threadIdx.x;      // 64 threads
    const int g = l >> 4, sl = l & 15;

    if (b < 24) {                   // W1: nt = b>>2, ks = b&3
        const int nt = b >> 2, ks = b & 3;
        const int o = nt * 16 + sl, kb = ks * 32 + g * 8;
        s16x8 v;
#pragma unroll
        for (int j = 0; j < 8; ++j) v[j] = (short)f2bf(W1[o * 128 + kb + j]);
        *(s16x8*)&w1f[b * 512 + l * 8] = v;
    } else if (b < 39) {            // W2 (out padded 72->80)
        const int f = b - 24, nt = f / 3, ks = f % 3;
        const int o = nt * 16 + sl, kb = ks * 32 + g * 8;
        s16x8 v;
#pragma unroll
        for (int j = 0; j < 8; ++j)
            v[j] = (short)((o < 72) ? f2bf(W2[o * 96 + kb + j]) : 0);
        *(s16x8*)&w2f[f * 512 + l * 8] = v;
    } else if (b < 51) {            // W3 (k padded 72->96)
        const int f = b - 39, nt = f / 3, ks = f % 3;
        const int o = nt * 16 + sl, kb = ks * 32 + g * 8;
        s16x8 v;
#pragma unroll
        for (int j = 0; j < 8; ++j)
            v[j] = (short)((kb + j < 72) ? f2bf(W3[o * 72 + kb + j]) : 0);
        *(s16x8*)&w3f[f * 512 + l * 8] = v;
    } else {                        // biases, zero-padded
        for (int i = l; i < 240; i += 64) {
            if (i < 96)       b1p[i] = b1[i];
            else if (i < 176) { int o = i - 96; b2p[o] = (o < 72) ? b2[o] : 0.f; }
            else              b3p[i - 176] = b3[i - 176];
        }
    }
}

// ---------------------------------------------------------------------------
// Main = R15 EXACT except the stage() row mapping: pass p of block b now
// covers rows b*512 + p*64 + wv*16 (was (b*4+wv)*128 + p*16). The block's 4
// waves read ADJACENT 8 KB chunks each pass -> one contiguous 32 KB DRAM
// burst per block per pass: 512 coherent streams instead of 2048 interleaved
// ones. Tests the hypothesis that HBM row-activate thrash (stream count >>
// bank population) is what caps x delivery at ~2.5 TB/s. The row permutation
// is semantics-free (rows processed identically; reduction symmetric).
// ---------------------------------------------------------------------------
__global__ __launch_bounds__(256, 1)
void mlp_main(const float* __restrict__ x,
              const f32x4* __restrict__ w1src,          // W1 frags + biases (1596 x 16 B)
              const unsigned short* __restrict__ w2f,   // 15 frags (hoisted to regs)
              const unsigned short* __restrict__ w3f,   // 12 frags (hoisted to regs)
              float* __restrict__ acc /* [65]: s[64], uu */)
{
    __shared__ __align__(16) unsigned char  wb[25536];        // W1 frags | b1 | b2 | b3
    __shared__ __align__(16) float          xbuf[4][2048];    // 32 KB: 8 KB/wave x tile
    __shared__ __align__(16) unsigned short act[4][16][HS];   // 13.3 KB wave-private
    __shared__ float sred[4][64];
    __shared__ float uured[4];

    const unsigned short* w1L = (const unsigned short*)wb;    // 24 frags
    const float* b1L = (const float*)(wb + 24576);            // 96
    const float* b2L = b1L + 96;                              // 80
    const float* b3L = b1L + 176;                             // 64

    const int tid  = threadIdx.x;
    const int lane = tid & 63;
    const int wv   = tid >> 6;
    const int g    = lane >> 4;
    const int sl   = lane & 15;
    const int g4   = g * 4;

    // ---- async stage of pass p's 16-row x tile (8 KB), swizzled source.
    // Pass-contiguous row map: rows = blockIdx*512 + p*64 + wv*16 .. +15
    auto stage = [&](int p) {
        const char* tb = (const char*)x
                       + ((size_t)blockIdx.x * 512 + (size_t)p * 64 + wv * 16) * 512;
        float* dst = &xbuf[wv][0];
#pragma unroll
        for (int c = 0; c < 8; ++c) {
            const unsigned off = (unsigned)(c * 1024 + lane * 16);
            const unsigned so  = off ^ (((off >> 9) & 7u) << 4);
            __builtin_amdgcn_global_load_lds(
                (const __attribute__((address_space(1))) void*)(tb + so),
                (__attribute__((address_space(3))) void*)(dst + c * 256),
                16, 0, 0);
        }
    };

    stage(0);                                   // in flight during W1 staging

    // ---- stage W1 + biases to LDS (25536 B = 1596 f32x4) ----
    for (int i = tid; i < 1596; i += 256)
        ((f32x4*)wb)[i] = w1src[i];

    // ---- hoist W2/W3 fragments into registers (loop-invariant) ----
    Frag W2r[5][3], W3r[4][3];
#pragma unroll
    for (int nt = 0; nt < 5; ++nt)
#pragma unroll
        for (int ks = 0; ks < 3; ++ks)
            W2r[nt][ks].v = *(const s16x8*)&w2f[(nt * 3 + ks) * 512 + lane * 8];
#pragma unroll
    for (int nt = 0; nt < 4; ++nt)
#pragma unroll
        for (int ks = 0; ks < 3; ++ks)
            W3r[nt][ks].v = *(const s16x8*)&w3f[(nt * 3 + ks) * 512 + lane * 8];

    __syncthreads();                            // weights visible; stage(0) drained

    float uu_part = 0.f;
    float s_part[4][4];
#pragma unroll
    for (int nt = 0; nt < 4; ++nt)
#pragma unroll
        for (int r = 0; r < 4; ++r) s_part[nt][r] = 0.f;

#pragma unroll 1
    for (int p = 0; p < PASSES; ++p) {
        // wait for this pass's staged tile
        asm volatile("s_waitcnt vmcnt(0)" ::: "memory");
        __builtin_amdgcn_sched_barrier(0);

        // ---- read x from LDS (swizzled) -> regs, cvt to B-frags (samples) ----
        const char* xb = (const char*)&xbuf[wv][0];
        const unsigned sw = (unsigned)((sl & 7) << 4);
        f32x4 t[8];
#pragma unroll
        for (int ks = 0; ks < 4; ++ks)
#pragma unroll
            for (int h = 0; h < 2; ++h)
                t[ks * 2 + h] = *(const f32x4*)(
                    xb + sl * 512 + ks * 128 + (((unsigned)(g * 32 + h * 16)) ^ sw));
        Frag X1[4];
#pragma unroll
        for (int ks = 0; ks < 4; ++ks)
#pragma unroll
            for (int j = 0; j < 4; ++j) {
                X1[ks].u[j]     = f2bf(t[ks * 2 + 0][j]);
                X1[ks].u[4 + j] = f2bf(t[ks * 2 + 1][j]);
            }

        // buffer free: issue next pass's stage; overlaps compute below
        __builtin_amdgcn_sched_barrier(0);
        if (p + 1 < PASSES) stage(p + 1);

        // ========== layer 1: D1 = W1 x x^T  (W1 = A operand, from LDS) ==========
        f32x4 D1[6];
#pragma unroll
        for (int nt = 0; nt < 6; ++nt)
            D1[nt] = *(const f32x4*)&b1L[nt * 16 + g4];
#pragma unroll
        for (int ks = 0; ks < 4; ++ks)
#pragma unroll
            for (int nt = 0; nt < 6; ++nt) {
                const s16x8 Wf = *(const s16x8*)&w1L[(nt * 4 + ks) * 512 + lane * 8];
                D1[nt] = __builtin_amdgcn_mfma_f32_16x16x32_bf16(Wf, X1[ks].v, D1[nt], 0, 0, 0);
            }
        // relu + contiguous b64 write: act[sample=sl][feat nt*16+g4 .. +3]
#pragma unroll
        for (int nt = 0; nt < 6; ++nt) {
            s16x4 q;
#pragma unroll
            for (int j = 0; j < 4; ++j) q[j] = (short)f2bf(fmaxf(D1[nt][j], 0.f));
            *(s16x4*)&act[wv][sl][nt * 16 + g4] = q;
        }

        // layer-2 B-frags: feats 0..95 of sample sl
        Frag A2[3];
#pragma unroll
        for (int ks = 0; ks < 3; ++ks)
            A2[ks].v = *(const s16x8*)&act[wv][sl][ks * 32 + g * 8];

        // zero pad feats 80..95 for the h2 tile (read by L3 ks=2)
        {
            const s16x4 z = (s16x4){0, 0, 0, 0};
            *(s16x4*)&act[wv][sl][80 + g4] = z;
        }

        // ========== layer 2: D2 = W2 x h1^T (W2 from registers) ==========
        f32x4 D2[5];
#pragma unroll
        for (int nt = 0; nt < 5; ++nt)
            D2[nt] = *(const f32x4*)&b2L[nt * 16 + g4];
#pragma unroll
        for (int ks = 0; ks < 3; ++ks)
#pragma unroll
            for (int nt = 0; nt < 5; ++nt)
                D2[nt] = __builtin_amdgcn_mfma_f32_16x16x32_bf16(W2r[nt][ks].v, A2[ks].v, D2[nt], 0, 0, 0);
#pragma unroll
        for (int nt = 0; nt < 5; ++nt) {
            s16x4 q;
#pragma unroll
            for (int j = 0; j < 4; ++j) q[j] = (short)f2bf(fmaxf(D2[nt][j], 0.f));
            *(s16x4*)&act[wv][sl][nt * 16 + g4] = q;
        }

        // layer-3 B-frags: h2 feats 0..95 (72..95 structurally zero)
        Frag A3[3];
#pragma unroll
        for (int ks = 0; ks < 3; ++ks)
            A3[ks].v = *(const s16x8*)&act[wv][sl][ks * 32 + g * 8];

        // ========== layer 3: D3 = W3 x h2^T (W3 from registers) ==========
        f32x4 D3[4];
#pragma unroll
        for (int nt = 0; nt < 4; ++nt)
            D3[nt] = *(const f32x4*)&b3L[nt * 16 + g4];
#pragma unroll
        for (int ks = 0; ks < 3; ++ks)
#pragma unroll
            for (int nt = 0; nt < 4; ++nt)
                D3[nt] = __builtin_amdgcn_mfma_f32_16x16x32_bf16(W3r[nt][ks].v, A3[ks].v, D3[nt], 0, 0, 0);

        // ===== epilogue (swapped): lane (g,sl) holds 16 outs of sample sl =====
        float ff = 0.f;
#pragma unroll
        for (int nt = 0; nt < 4; ++nt)
#pragma unroll
            for (int r = 0; r < 4; ++r)
                ff = fmaf(D3[nt][r], D3[nt][r], ff);
        ff += __shfl_xor(ff, 16, 64);
        ff += __shfl_xor(ff, 32, 64);
        const float inv = 1.f / fmaxf(sqrtf(ff), EPSF);
        uu_part = fmaf(ff * inv, inv, uu_part);
#pragma unroll
        for (int nt = 0; nt < 4; ++nt)
#pragma unroll
            for (int r = 0; r < 4; ++r)
                s_part[nt][r] = fmaf(D3[nt][r], inv, s_part[nt][r]);
    }

    // ---- once per wave: s over sl lanes; uu over all lanes ----
#pragma unroll
    for (int nt = 0; nt < 4; ++nt)
#pragma unroll
        for (int r = 0; r < 4; ++r) {
            s_part[nt][r] += __shfl_xor(s_part[nt][r], 1, 64);
            s_part[nt][r] += __shfl_xor(s_part[nt][r], 2, 64);
            s_part[nt][r] += __shfl_xor(s_part[nt][r], 4, 64);
            s_part[nt][r] += __shfl_xor(s_part[nt][r], 8, 64);
        }
#pragma unroll
    for (int off = 1; off < 64; off <<= 1)
        uu_part += __shfl_xor(uu_part, off, 64);

    if (sl == 0) {
#pragma unroll
        for (int nt = 0; nt < 4; ++nt) {
            f32x4 v = {s_part[nt][0], s_part[nt][1], s_part[nt][2], s_part[nt][3]};
            *(f32x4*)&sred[wv][nt * 16 + g4] = v;
        }
    }
    if (lane == 0) uured[wv] = uu_part * 0.25f;
    __syncthreads();

    if (tid < 64) {
        const float t2 = sred[0][tid] + sred[1][tid] + sred[2][tid] + sred[3][tid];
        atomicAdd(&acc[tid], t2);
    }
    if (tid == 0)
        atomicAdd(&acc[64], uured[0] + uured[1] + uured[2] + uured[3]);
}

__global__ void finalize_k(const float* __restrict__ acc, float* __restrict__ out)
{
    float s = acc[threadIdx.x];
    float d = s * s;
#pragma unroll
    for (int off = 32; off > 0; off >>= 1)
        d += __shfl_xor(d, off, 64);
    if (threadIdx.x == 0)
        out[0] = 0.5f * (d - acc[64]) / (float)NROWS;
}

extern "C" void kernel_launch(void* const* d_in, const int* in_sizes, int n_in,
                              void* d_out, int out_size, void* d_ws, size_t ws_size,
                              hipStream_t stream)
{
    const float* x  = (const float*)d_in[0];
    const float* W1 = (const float*)d_in[1];
    const float* b1 = (const float*)d_in[2];
    const float* W2 = (const float*)d_in[3];
    const float* b2 = (const float*)d_in[4];
    const float* W3 = (const float*)d_in[5];
    const float* b3 = (const float*)d_in[6];

    char* ws = (char*)d_ws;
    // layout: [acc 1024][w1f 24576][b1 384][b2 320][b3 256][w2f 15360][w3f 12288]
    float*          acc = (float*)ws;
    unsigned short* w1f = (unsigned short*)(ws + 1024);
    float*          b1p = (float*)(ws + 25600);
    float*          b2p = (float*)(ws + 25984);
    float*          b3p = (float*)(ws + 26304);
    unsigned short* w2f = (unsigned short*)(ws + 26560);
    unsigned short* w3f = (unsigned short*)(ws + 41920);

    hipMemsetAsync(acc, 0, 1024, stream);
    repack<<<52, 64, 0, stream>>>(W1, b1, W2, b2, W3, b3, w1f, w2f, w3f, b1p, b2p, b3p);
    // 512 blocks x 4 waves x 8 passes x 16 rows = 262144 rows
    mlp_main<<<NROWS / (4 * PASSES * 16), 256, 0, stream>>>(
        x, (const f32x4*)(ws + 1024), w2f, w3f, acc);
    finalize_k<<<1, 64, 0, stream>>>(acc, (float*)d_out);
}